// Round 9
// baseline (694.315 us; speedup 1.0000x reference)
//
#include <hip/hip_runtime.h>
#include <cstdint>
#include <cstddef>

// ---------------------------------------------------------------------------
// GATv2 edge predictor, fp32 throughout.
//   preprocessing: cnt -> 3-kernel scan -> csr (int2 (e,s) per slot)
//   Self-loop handled analytically (mean(attr)@We == mean(attr@We)): per-node
//   eaW sums accumulated during the edge loop, self-loop processed last.
//   per GAT layer:
//     gemm2: xl = x@Wl+bl AND xr = x@Wr+br in one kernel (shared A tile)
//     node_fused{2,1}: one wave/node, ONLINE softmax, half-wave mapping,
//       We pinned in VGPRs via asm (compiler refused residency: r7 VGPR=36),
//       3-buffer unroll-by-3 pipeline (prefetch distance ~2.5 iters).
//   then: aa = h2@Wm1_top ; bb = h2@Wm1_bot+bm1 (edge MLP folded to nodes)
//   edge_mlp: 4 edges/wave, out[e] = relu(aa[s]+bb[d]).Wm2 + bm2
// ---------------------------------------------------------------------------

__device__ __forceinline__ float half_sum(float v) {
#pragma unroll
  for (int o = 1; o <= 16; o <<= 1) v += __shfl_xor(v, o, 64);
  return v;
}

__global__ __launch_bounds__(256) void cnt_kernel(const int* __restrict__ dst,
                                                  int* __restrict__ cnt, int E) {
  int e = blockIdx.x * 256 + threadIdx.x;
  if (e < E) atomicAdd(&cnt[dst[e]], 1);
}

__global__ __launch_bounds__(256) void scan_blocksum_kernel(
    const int* __restrict__ cnt, int* __restrict__ partial, int Nn) {
  int i = blockIdx.x * 256 + threadIdx.x;
  int v = (i < Nn) ? cnt[i] : 0;
#pragma unroll
  for (int o = 32; o > 0; o >>= 1) v += __shfl_xor(v, o, 64);
  __shared__ int ws[4];
  if ((threadIdx.x & 63) == 0) ws[threadIdx.x >> 6] = v;
  __syncthreads();
  if (threadIdx.x == 0) partial[blockIdx.x] = ws[0] + ws[1] + ws[2] + ws[3];
}

__global__ __launch_bounds__(256) void scan_partial_kernel(
    int* __restrict__ partial, int* __restrict__ rowptr, int nb, int Nn, int E) {
  __shared__ int buf[256];
  int t = threadIdx.x;
  int v = (t < nb) ? partial[t] : 0;
  buf[t] = v;
  __syncthreads();
  for (int o = 1; o < 256; o <<= 1) {
    int u = (t >= o) ? buf[t - o] : 0;
    __syncthreads();
    buf[t] += u;
    __syncthreads();
  }
  partial[t] = (t == 0) ? 0 : buf[t - 1];
  if (t == 0) rowptr[Nn] = E;
}

__global__ __launch_bounds__(256) void scan_write_kernel(
    const int* __restrict__ cnt, const int* __restrict__ partial,
    int* __restrict__ rowptr, int* __restrict__ cursor, int Nn) {
  __shared__ int buf[256];
  int i = blockIdx.x * 256 + threadIdx.x;
  int t = threadIdx.x;
  int v = (i < Nn) ? cnt[i] : 0;
  buf[t] = v;
  __syncthreads();
  for (int o = 1; o < 256; o <<= 1) {
    int u = (t >= o) ? buf[t - o] : 0;
    __syncthreads();
    buf[t] += u;
    __syncthreads();
  }
  if (i < Nn) {
    int r = partial[blockIdx.x] + buf[t] - v;
    rowptr[i] = r;
    cursor[i] = r;
  }
}

__global__ __launch_bounds__(256) void csr_build_kernel(
    const int* __restrict__ src, const int* __restrict__ dst,
    int* __restrict__ cursor, int2* __restrict__ es, int E) {
  int e = blockIdx.x * 256 + threadIdx.x;
  if (e >= E) return;
  int s = src[e], d = dst[e];
  int pos = atomicAdd(&cursor[d], 1);
  es[pos] = make_int2(e, s);
}

// Dual GEMM: C1[M,NC] = A@W1 (+b1), C2[M,NC] = A@W2 (+b2); shared A tile.
template <int K, int NC>
__global__ __launch_bounds__(256, 4) void gemm2_kernel(
    const float* __restrict__ A, const float* __restrict__ W1,
    const float* __restrict__ b1, float* __restrict__ C1,
    const float* __restrict__ W2, const float* __restrict__ b2,
    float* __restrict__ C2, int M) {
  const int BM = 64;
  const int CQ = NC / 4;
  const int RP = BM / (256 / CQ);
  __shared__ float Alds[BM * K];
  int row0 = blockIdx.x * BM;
  for (int i = threadIdx.x; i < BM * K / 4; i += 256) {
    int r = i / (K / 4);
    float4 v = make_float4(0.f, 0.f, 0.f, 0.f);
    if (row0 + r < M) v = ((const float4*)A)[(size_t)(row0 + r) * (K / 4) + (i % (K / 4))];
    ((float4*)Alds)[i] = v;
  }
  __syncthreads();
  int cq = threadIdx.x % CQ;
  int rg = threadIdx.x / CQ;
  float4 acc1[RP], acc2[RP];
#pragma unroll
  for (int r = 0; r < RP; r++) {
    acc1[r] = make_float4(0.f, 0.f, 0.f, 0.f);
    acc2[r] = make_float4(0.f, 0.f, 0.f, 0.f);
  }
  const float4* W14 = (const float4*)W1;
  const float4* W24 = (const float4*)W2;
  for (int k = 0; k < K; k += 4) {
    float4 u0 = W14[(size_t)(k + 0) * CQ + cq];
    float4 u1 = W14[(size_t)(k + 1) * CQ + cq];
    float4 u2 = W14[(size_t)(k + 2) * CQ + cq];
    float4 u3 = W14[(size_t)(k + 3) * CQ + cq];
    float4 v0 = W24[(size_t)(k + 0) * CQ + cq];
    float4 v1 = W24[(size_t)(k + 1) * CQ + cq];
    float4 v2 = W24[(size_t)(k + 2) * CQ + cq];
    float4 v3 = W24[(size_t)(k + 3) * CQ + cq];
#pragma unroll
    for (int r = 0; r < RP; r++) {
      float4 a = ((const float4*)Alds)[(rg * RP + r) * (K / 4) + (k >> 2)];
      acc1[r].x = fmaf(a.x, u0.x, acc1[r].x);
      acc1[r].y = fmaf(a.x, u0.y, acc1[r].y);
      acc1[r].z = fmaf(a.x, u0.z, acc1[r].z);
      acc1[r].w = fmaf(a.x, u0.w, acc1[r].w);
      acc1[r].x = fmaf(a.y, u1.x, acc1[r].x);
      acc1[r].y = fmaf(a.y, u1.y, acc1[r].y);
      acc1[r].z = fmaf(a.y, u1.z, acc1[r].z);
      acc1[r].w = fmaf(a.y, u1.w, acc1[r].w);
      acc1[r].x = fmaf(a.z, u2.x, acc1[r].x);
      acc1[r].y = fmaf(a.z, u2.y, acc1[r].y);
      acc1[r].z = fmaf(a.z, u2.z, acc1[r].z);
      acc1[r].w = fmaf(a.z, u2.w, acc1[r].w);
      acc1[r].x = fmaf(a.w, u3.x, acc1[r].x);
      acc1[r].y = fmaf(a.w, u3.y, acc1[r].y);
      acc1[r].z = fmaf(a.w, u3.z, acc1[r].z);
      acc1[r].w = fmaf(a.w, u3.w, acc1[r].w);
      acc2[r].x = fmaf(a.x, v0.x, acc2[r].x);
      acc2[r].y = fmaf(a.x, v0.y, acc2[r].y);
      acc2[r].z = fmaf(a.x, v0.z, acc2[r].z);
      acc2[r].w = fmaf(a.x, v0.w, acc2[r].w);
      acc2[r].x = fmaf(a.y, v1.x, acc2[r].x);
      acc2[r].y = fmaf(a.y, v1.y, acc2[r].y);
      acc2[r].z = fmaf(a.y, v1.z, acc2[r].z);
      acc2[r].w = fmaf(a.y, v1.w, acc2[r].w);
      acc2[r].x = fmaf(a.z, v2.x, acc2[r].x);
      acc2[r].y = fmaf(a.z, v2.y, acc2[r].y);
      acc2[r].z = fmaf(a.z, v2.z, acc2[r].z);
      acc2[r].w = fmaf(a.z, v2.w, acc2[r].w);
      acc2[r].x = fmaf(a.w, v3.x, acc2[r].x);
      acc2[r].y = fmaf(a.w, v3.y, acc2[r].y);
      acc2[r].z = fmaf(a.w, v3.z, acc2[r].z);
      acc2[r].w = fmaf(a.w, v3.w, acc2[r].w);
    }
  }
  float4 bb1 = b1 ? ((const float4*)b1)[cq] : make_float4(0.f, 0.f, 0.f, 0.f);
  float4 bb2 = b2 ? ((const float4*)b2)[cq] : make_float4(0.f, 0.f, 0.f, 0.f);
#pragma unroll
  for (int r = 0; r < RP; r++) {
    int row = row0 + rg * RP + r;
    if (row < M) {
      ((float4*)C1)[(size_t)row * CQ + cq] =
          make_float4(acc1[r].x + bb1.x, acc1[r].y + bb1.y, acc1[r].z + bb1.z,
                      acc1[r].w + bb1.w);
      ((float4*)C2)[(size_t)row * CQ + cq] =
          make_float4(acc2[r].x + bb2.x, acc2[r].y + bb2.y, acc2[r].z + bb2.z,
                      acc2[r].w + bb2.w);
    }
  }
}

// H=2 fused node pass: lanes 0-31 = head0, lanes 32-63 = head1, float2 ch/lane.
// We pinned in VGPRs; 3-buffer unroll-by-3 pipeline; analytic self-loop last.
template <int ELU>
__global__ __launch_bounds__(256, 4) void node_fused2_kernel(
    const int* __restrict__ rowptr, const int2* __restrict__ es,
    const float* __restrict__ edge_attr, const float* __restrict__ We,
    const float* __restrict__ att, const float* __restrict__ xl,
    const float* __restrict__ xr, const float* __restrict__ bias,
    float* __restrict__ out, int Nn) {
  int wid = blockIdx.x * 4 + (threadIdx.x >> 6);
  if (wid >= Nn) return;
  int l = threadIdx.x & 63;
  int ch = ((l >> 5) << 6) | ((l & 31) << 1);  // head*64 + 2*q
  float2 we[16];
#pragma unroll
  for (int k = 0; k < 16; k++) we[k] = *(const float2*)(We + k * 128 + ch);
#pragma unroll
  for (int k = 0; k < 16; k++)
    asm volatile("" : "+v"(we[k].x), "+v"(we[k].y));  // force VGPR residency
  float2 xr2 = *(const float2*)(xr + (size_t)wid * 128 + ch);
  float2 at2 = *(const float2*)(att + ch);
  int start = __builtin_amdgcn_readfirstlane(rowptr[wid]);
  int end = __builtin_amdgcn_readfirstlane(rowptr[wid + 1]);
  float m = -1e30f, sden = 0.f, accx = 0.f, accy = 0.f;
  float sax = 0.f, say = 0.f;  // per-channel eaW sums (for analytic self-loop)
  if (end > start) {
    float4 a0A, a1A, a2A, a3A, a0B, a1B, a2B, a3B, a0C, a1C, a2C, a3C;
    float2 xA, xB, xC;
    auto ldbuf = [&](float4& b0, float4& b1, float4& b2, float4& b3, float2& bx,
                     int jj) {
      int2 ii = es[jj];
      const float4* p4 = (const float4*)(edge_attr + (size_t)ii.x * 16);
      b0 = p4[0]; b1 = p4[1]; b2 = p4[2]; b3 = p4[3];
      bx = *(const float2*)(xl + (size_t)ii.y * 128 + ch);
    };
    auto step = [&](float4& b0, float4& b1, float4& b2, float4& b3, float2& bx,
                    int jj) {
      float av[16] = {b0.x, b0.y, b0.z, b0.w, b1.x, b1.y, b1.z, b1.w,
                      b2.x, b2.y, b2.z, b2.w, b3.x, b3.y, b3.z, b3.w};
      float Xx = bx.x, Xy = bx.y;
      ldbuf(b0, b1, b2, b3, bx, min(jj + 3, end - 1));  // refill early
      float ex = 0.f, ey = 0.f;
#pragma unroll
      for (int k = 0; k < 16; k++) {
        ex = fmaf(av[k], we[k].x, ex);
        ey = fmaf(av[k], we[k].y, ey);
      }
      sax += ex;
      say += ey;
      float mx = Xx + xr2.x + ex;
      float my = Xy + xr2.y + ey;
      mx = (mx >= 0.f) ? mx : 0.2f * mx;  // LeakyReLU(0.2)
      my = (my >= 0.f) ? my : 0.2f * my;
      float p = half_sum(fmaf(at2.x, mx, at2.y * my));
      float nm = fmaxf(m, p);
      float r = __expf(m - nm), ep = __expf(p - nm);
      sden = fmaf(sden, r, ep);
      accx = fmaf(accx, r, ep * Xx);
      accy = fmaf(accy, r, ep * Xy);
      m = nm;
    };
    ldbuf(a0A, a1A, a2A, a3A, xA, start);
    ldbuf(a0B, a1B, a2B, a3B, xB, min(start + 1, end - 1));
    ldbuf(a0C, a1C, a2C, a3C, xC, min(start + 2, end - 1));
    int j = start;
    for (; j + 2 < end; j += 3) {
      step(a0A, a1A, a2A, a3A, xA, j);
      step(a0B, a1B, a2B, a3B, xB, j + 1);
      step(a0C, a1C, a2C, a3C, xC, j + 2);
    }
    if (j < end) { step(a0A, a1A, a2A, a3A, xA, j); j++; }
    if (j < end) { step(a0B, a1B, a2B, a3B, xB, j); j++; }
  }
  // analytic self loop: eaW = mean of incident eaW (0 if isolated)
  {
    float denom = 1.f / fmaxf((float)(end - start), 1.f);
    float2 Xs = *(const float2*)(xl + (size_t)wid * 128 + ch);
    float mx = Xs.x + xr2.x + sax * denom;
    float my = Xs.y + xr2.y + say * denom;
    mx = (mx >= 0.f) ? mx : 0.2f * mx;
    my = (my >= 0.f) ? my : 0.2f * my;
    float p = half_sum(fmaf(at2.x, mx, at2.y * my));
    float nm = fmaxf(m, p);
    float r = __expf(m - nm), ep = __expf(p - nm);
    sden = fmaf(sden, r, ep);
    accx = fmaf(accx, r, ep * Xs.x);
    accy = fmaf(accy, r, ep * Xs.y);
  }
  float inv = 1.f / sden;
  float2 b2 = *(const float2*)(bias + ch);
  float vx = fmaf(accx, inv, b2.x);
  float vy = fmaf(accy, inv, b2.y);
  if (ELU) {
    vx = (vx > 0.f) ? vx : expm1f(vx);
    vy = (vy > 0.f) ? vy : expm1f(vy);
  }
  *(float2*)(out + (size_t)wid * 128 + ch) = make_float2(vx, vy);
}

// H=1 fused node pass: half-wave per edge (2 edges/pair-step), float2 ch/lane,
// 3-buffer pipeline over pairs (distance 6 edges), state merge + self-loop.
__global__ __launch_bounds__(256, 4) void node_fused1_kernel(
    const int* __restrict__ rowptr, const int2* __restrict__ es,
    const float* __restrict__ edge_attr, const float* __restrict__ We,
    const float* __restrict__ att, const float* __restrict__ xl,
    const float* __restrict__ xr, const float* __restrict__ bias,
    float* __restrict__ out, int Nn) {
  int wid = blockIdx.x * 4 + (threadIdx.x >> 6);
  if (wid >= Nn) return;
  int l = threadIdx.x & 63;
  int half = l >> 5;
  int ch = (l & 31) << 1;
  float2 we[16];
#pragma unroll
  for (int k = 0; k < 16; k++) we[k] = *(const float2*)(We + k * 64 + ch);
#pragma unroll
  for (int k = 0; k < 16; k++)
    asm volatile("" : "+v"(we[k].x), "+v"(we[k].y));
  float2 xr2 = *(const float2*)(xr + (size_t)wid * 64 + ch);
  float2 at2 = *(const float2*)(att + ch);
  int start = __builtin_amdgcn_readfirstlane(rowptr[wid]);
  int end = __builtin_amdgcn_readfirstlane(rowptr[wid + 1]);
  float m = -1e30f, sden = 0.f, accx = 0.f, accy = 0.f;
  float sax = 0.f, say = 0.f;
  if (end > start) {
    float4 a0A, a1A, a2A, a3A, a0B, a1B, a2B, a3B, a0C, a1C, a2C, a3C;
    float2 xA, xB, xC;
    auto ldbuf = [&](float4& b0, float4& b1, float4& b2, float4& b3, float2& bx,
                     int base) {
      int jj = min(base + half, end - 1);
      int2 ii = es[jj];
      const float4* p4 = (const float4*)(edge_attr + (size_t)ii.x * 16);
      b0 = p4[0]; b1 = p4[1]; b2 = p4[2]; b3 = p4[3];
      bx = *(const float2*)(xl + (size_t)ii.y * 64 + ch);
    };
    auto step = [&](float4& b0, float4& b1, float4& b2, float4& b3, float2& bx,
                    int base) {
      float av[16] = {b0.x, b0.y, b0.z, b0.w, b1.x, b1.y, b1.z, b1.w,
                      b2.x, b2.y, b2.z, b2.w, b3.x, b3.y, b3.z, b3.w};
      float Xx = bx.x, Xy = bx.y;
      ldbuf(b0, b1, b2, b3, bx, base + 6);  // refill 3 pairs ahead
      float ex = 0.f, ey = 0.f;
#pragma unroll
      for (int k = 0; k < 16; k++) {
        ex = fmaf(av[k], we[k].x, ex);
        ey = fmaf(av[k], we[k].y, ey);
      }
      bool dead = (base + half) >= end;  // odd tail in half 1
      sax += dead ? 0.f : ex;
      say += dead ? 0.f : ey;
      float mx = Xx + xr2.x + ex;
      float my = Xy + xr2.y + ey;
      mx = (mx >= 0.f) ? mx : 0.2f * mx;
      my = (my >= 0.f) ? my : 0.2f * my;
      float p = half_sum(fmaf(at2.x, mx, at2.y * my));
      p = dead ? -1e30f : p;
      float nm = fmaxf(m, p);
      float r = __expf(m - nm), ep = __expf(p - nm);
      ep = dead ? 0.f : ep;
      sden = fmaf(sden, r, ep);
      accx = fmaf(accx, r, ep * Xx);
      accy = fmaf(accy, r, ep * Xy);
      m = nm;
    };
    ldbuf(a0A, a1A, a2A, a3A, xA, start);
    ldbuf(a0B, a1B, a2B, a3B, xB, start + 2);
    ldbuf(a0C, a1C, a2C, a3C, xC, start + 4);
    int j = start;
    for (; j + 5 < end; j += 6) {
      step(a0A, a1A, a2A, a3A, xA, j);
      step(a0B, a1B, a2B, a3B, xB, j + 2);
      step(a0C, a1C, a2C, a3C, xC, j + 4);
    }
    if (j < end) { step(a0A, a1A, a2A, a3A, xA, j); j += 2; }
    if (j < end) { step(a0B, a1B, a2B, a3B, xB, j); j += 2; }
    if (j < end) { step(a0C, a1C, a2C, a3C, xC, j); j += 2; }
  }
  // merge the two half-wave states
  float mo = __shfl_xor(m, 32, 64);
  float so = __shfl_xor(sden, 32, 64);
  float aox = __shfl_xor(accx, 32, 64);
  float aoy = __shfl_xor(accy, 32, 64);
  float M = fmaxf(m, mo);
  float ra = __expf(m - M), rb = __expf(mo - M);
  float S = fmaf(sden, ra, so * rb);
  float AX = fmaf(accx, ra, aox * rb);
  float AY = fmaf(accy, ra, aoy * rb);
  float saxt = sax + __shfl_xor(sax, 32, 64);
  float sayt = say + __shfl_xor(say, 32, 64);
  // analytic self loop
  {
    float denom = 1.f / fmaxf((float)(end - start), 1.f);
    float2 Xs = *(const float2*)(xl + (size_t)wid * 64 + ch);
    float mx = Xs.x + xr2.x + saxt * denom;
    float my = Xs.y + xr2.y + sayt * denom;
    mx = (mx >= 0.f) ? mx : 0.2f * mx;
    my = (my >= 0.f) ? my : 0.2f * my;
    float p = half_sum(fmaf(at2.x, mx, at2.y * my));
    float nm = fmaxf(M, p);
    float r = __expf(M - nm), ep = __expf(p - nm);
    S = fmaf(S, r, ep);
    AX = fmaf(AX, r, ep * Xs.x);
    AY = fmaf(AY, r, ep * Xs.y);
  }
  if (half == 0) {
    float inv = 1.f / S;
    float2 b2 = *(const float2*)(bias + ch);
    *(float2*)(out + (size_t)wid * 64 + ch) =
        make_float2(fmaf(AX, inv, b2.x), fmaf(AY, inv, b2.y));
  }
}

// 4 edges per wave; 16 lanes x float4 per edge.
__global__ __launch_bounds__(256) void edge_mlp_kernel(
    const int* __restrict__ src, const int* __restrict__ dst,
    const float* __restrict__ aa, const float* __restrict__ bb,
    const float* __restrict__ Wm2, const float* __restrict__ bm2,
    float* __restrict__ out, int E) {
  int t = blockIdx.x * 256 + threadIdx.x;
  int eid = t >> 4;
  if (eid >= E) return;
  int g = threadIdx.x & 15;
  float4 w = ((const float4*)Wm2)[g];
  int s = src[eid], d = dst[eid];
  float4 za = ((const float4*)aa)[(size_t)s * 16 + g];
  float4 zb = ((const float4*)bb)[(size_t)d * 16 + g];
  float p = fmaxf(za.x + zb.x, 0.f) * w.x;
  p = fmaf(fmaxf(za.y + zb.y, 0.f), w.y, p);
  p = fmaf(fmaxf(za.z + zb.z, 0.f), w.z, p);
  p = fmaf(fmaxf(za.w + zb.w, 0.f), w.w, p);
#pragma unroll
  for (int o = 8; o > 0; o >>= 1) p += __shfl_xor(p, o, 64);
  if (g == 0) out[eid] = p + bm2[0];
}

extern "C" void kernel_launch(void* const* d_in, const int* in_sizes, int n_in,
                              void* d_out, int out_size, void* d_ws,
                              size_t ws_size, hipStream_t stream) {
  const float* x = (const float*)d_in[0];
  const int* ei = (const int*)d_in[1];
  const float* edge_attr = (const float*)d_in[2];
  const float* Wl1 = (const float*)d_in[3];
  const float* bl1 = (const float*)d_in[4];
  const float* Wr1 = (const float*)d_in[5];
  const float* br1 = (const float*)d_in[6];
  const float* We1 = (const float*)d_in[7];
  const float* att1 = (const float*)d_in[8];
  const float* b1 = (const float*)d_in[9];
  const float* Wl2 = (const float*)d_in[10];
  const float* bl2 = (const float*)d_in[11];
  const float* Wr2 = (const float*)d_in[12];
  const float* br2 = (const float*)d_in[13];
  const float* We2 = (const float*)d_in[14];
  const float* att2 = (const float*)d_in[15];
  const float* b2 = (const float*)d_in[16];
  const float* Wm1 = (const float*)d_in[17];
  const float* bm1 = (const float*)d_in[18];
  const float* Wm2 = (const float*)d_in[19];
  const float* bm2 = (const float*)d_in[20];

  const int Nn = in_sizes[0] / 128;  // 50000
  const int E = in_sizes[1] / 2;     // 800000
  const int* src = ei;
  const int* dst = ei + E;
  const int nb = (Nn + 255) / 256;

  char* ws = (char*)d_ws;
  size_t off = 0;
  auto alloc = [&](size_t bytes) -> char* {
    char* p = ws + off;
    off += (bytes + 255) & ~(size_t)255;
    return p;
  };
  int* cnt = (int*)alloc((size_t)Nn * 4);
  int* rowptr = (int*)alloc((size_t)(Nn + 1) * 4);
  int* cursor = (int*)alloc((size_t)Nn * 4);
  int* partial = (int*)alloc(256 * 4);
  int2* es = (int2*)alloc((size_t)E * 8);
  float* xl = (float*)alloc((size_t)Nn * 128 * 4);
  float* xr = (float*)alloc((size_t)Nn * 128 * 4);
  float* h1 = (float*)alloc((size_t)Nn * 128 * 4);
  float* h2 = (float*)alloc((size_t)Nn * 64 * 4);
  float* aa = xl;  // reuse after layer-2 node pass
  float* bb = xr;

  hipMemsetAsync(cnt, 0, (size_t)Nn * 4, stream);

  // --- graph preprocessing ---
  cnt_kernel<<<(E + 255) / 256, 256, 0, stream>>>(dst, cnt, E);
  scan_blocksum_kernel<<<nb, 256, 0, stream>>>(cnt, partial, Nn);
  scan_partial_kernel<<<1, 256, 0, stream>>>(partial, rowptr, nb, Nn, E);
  scan_write_kernel<<<nb, 256, 0, stream>>>(cnt, partial, rowptr, cursor, Nn);
  csr_build_kernel<<<(E + 255) / 256, 256, 0, stream>>>(src, dst, cursor, es, E);

  // --- layer 1 (heads=2, hid=64) ---
  gemm2_kernel<128, 128><<<(Nn + 63) / 64, 256, 0, stream>>>(
      x, Wl1, bl1, xl, Wr1, br1, xr, Nn);
  node_fused2_kernel<1><<<(Nn + 3) / 4, 256, 0, stream>>>(
      rowptr, es, edge_attr, We1, att1, xl, xr, b1, h1, Nn);

  // --- layer 2 (heads=1, out=64) ---
  gemm2_kernel<128, 64><<<(Nn + 63) / 64, 256, 0, stream>>>(
      h1, Wl2, bl2, xl, Wr2, br2, xr, Nn);
  node_fused1_kernel<<<(Nn + 3) / 4, 256, 0, stream>>>(
      rowptr, es, edge_attr, We2, att2, xl, xr, b2, h2, Nn);

  // --- edge MLP, folded: z = relu(h2[s]@Wm1_top + h2[d]@Wm1_bot + bm1) ---
  gemm2_kernel<64, 64><<<(Nn + 63) / 64, 256, 0, stream>>>(
      h2, Wm1, nullptr, aa, Wm1 + 64 * 64, bm1, bb, Nn);
  edge_mlp_kernel<<<(E * 16 + 255) / 256, 256, 0, stream>>>(src, dst, aa, bb,
                                                            Wm2, bm2,
                                                            (float*)d_out, E);
}

// Round 10
// 671.504 us; speedup vs baseline: 1.0340x; 1.0340x over previous
//
#include <hip/hip_runtime.h>
#include <cstdint>
#include <cstddef>

// ---------------------------------------------------------------------------
// GATv2 edge predictor, fp32 throughout.
//   preprocessing: cnt -> 3-kernel scan -> csr (sperm + pperm) -> ea_scatter
//     (edge_attr permuted into CSR order so node passes stream it uniformly).
//   Self-loop handled analytically (mean(attr)@We == mean(attr@We)).
//   per GAT layer:
//     gemm2: xl = x@Wl+bl AND xr = x@Wr+br in one kernel (shared A tile)
//     node_fused{2,1}: one wave/node, ONLINE softmax, BATCH-OF-4 edges:
//       We staged in LDS, each we[k] read once per batch and applied to 4
//       edges (4x less We traffic - the round-9 bottleneck), ea rows read as
//       uniform scalar loads from ea_sorted, one rescale + 4 exps per batch.
//   then: aa = h2@Wm1_top ; bb = h2@Wm1_bot+bm1 (edge MLP folded to nodes)
//   edge_mlp: 4 edges/wave, out[e] = relu(aa[s]+bb[d]).Wm2 + bm2
// ---------------------------------------------------------------------------

__global__ __launch_bounds__(256) void cnt_kernel(const int* __restrict__ dst,
                                                  int* __restrict__ cnt, int E) {
  int e = blockIdx.x * 256 + threadIdx.x;
  if (e < E) atomicAdd(&cnt[dst[e]], 1);
}

__global__ __launch_bounds__(256) void scan_blocksum_kernel(
    const int* __restrict__ cnt, int* __restrict__ partial, int Nn) {
  int i = blockIdx.x * 256 + threadIdx.x;
  int v = (i < Nn) ? cnt[i] : 0;
#pragma unroll
  for (int o = 32; o > 0; o >>= 1) v += __shfl_xor(v, o, 64);
  __shared__ int ws[4];
  if ((threadIdx.x & 63) == 0) ws[threadIdx.x >> 6] = v;
  __syncthreads();
  if (threadIdx.x == 0) partial[blockIdx.x] = ws[0] + ws[1] + ws[2] + ws[3];
}

__global__ __launch_bounds__(256) void scan_partial_kernel(
    int* __restrict__ partial, int* __restrict__ rowptr, int nb, int Nn, int E) {
  __shared__ int buf[256];
  int t = threadIdx.x;
  int v = (t < nb) ? partial[t] : 0;
  buf[t] = v;
  __syncthreads();
  for (int o = 1; o < 256; o <<= 1) {
    int u = (t >= o) ? buf[t - o] : 0;
    __syncthreads();
    buf[t] += u;
    __syncthreads();
  }
  partial[t] = (t == 0) ? 0 : buf[t - 1];
  if (t == 0) rowptr[Nn] = E;
}

__global__ __launch_bounds__(256) void scan_write_kernel(
    const int* __restrict__ cnt, const int* __restrict__ partial,
    int* __restrict__ rowptr, int* __restrict__ cursor, int Nn) {
  __shared__ int buf[256];
  int i = blockIdx.x * 256 + threadIdx.x;
  int t = threadIdx.x;
  int v = (i < Nn) ? cnt[i] : 0;
  buf[t] = v;
  __syncthreads();
  for (int o = 1; o < 256; o <<= 1) {
    int u = (t >= o) ? buf[t - o] : 0;
    __syncthreads();
    buf[t] += u;
    __syncthreads();
  }
  if (i < Nn) {
    int r = partial[blockIdx.x] + buf[t] - v;
    rowptr[i] = r;
    cursor[i] = r;
  }
}

// CSR by dst: sperm[pos] = src, pperm[e] = pos.
__global__ __launch_bounds__(256) void csr_build_kernel(
    const int* __restrict__ src, const int* __restrict__ dst,
    int* __restrict__ cursor, int* __restrict__ sperm, int* __restrict__ pperm,
    int E) {
  int e = blockIdx.x * 256 + threadIdx.x;
  if (e >= E) return;
  int s = src[e], d = dst[e];
  int pos = atomicAdd(&cursor[d], 1);
  sperm[pos] = s;
  pperm[e] = pos;
}

// Permute edge_attr into CSR slot order (coalesced read, 64B scattered write).
__global__ __launch_bounds__(256) void ea_scatter_kernel(
    const float* __restrict__ edge_attr, const int* __restrict__ pperm,
    float* __restrict__ ea_sorted, int E) {
  int t = blockIdx.x * 256 + threadIdx.x;
  if (t >= E * 16) return;
  int e = t >> 4, k = t & 15;
  ea_sorted[(size_t)pperm[e] * 16 + k] = edge_attr[t];
}

// Dual GEMM: C1[M,NC] = A@W1 (+b1), C2[M,NC] = A@W2 (+b2); shared A tile.
template <int K, int NC>
__global__ __launch_bounds__(256, 4) void gemm2_kernel(
    const float* __restrict__ A, const float* __restrict__ W1,
    const float* __restrict__ b1, float* __restrict__ C1,
    const float* __restrict__ W2, const float* __restrict__ b2,
    float* __restrict__ C2, int M) {
  const int BM = 64;
  const int CQ = NC / 4;
  const int RP = BM / (256 / CQ);
  __shared__ float Alds[BM * K];
  int row0 = blockIdx.x * BM;
  for (int i = threadIdx.x; i < BM * K / 4; i += 256) {
    int r = i / (K / 4);
    float4 v = make_float4(0.f, 0.f, 0.f, 0.f);
    if (row0 + r < M) v = ((const float4*)A)[(size_t)(row0 + r) * (K / 4) + (i % (K / 4))];
    ((float4*)Alds)[i] = v;
  }
  __syncthreads();
  int cq = threadIdx.x % CQ;
  int rg = threadIdx.x / CQ;
  float4 acc1[RP], acc2[RP];
#pragma unroll
  for (int r = 0; r < RP; r++) {
    acc1[r] = make_float4(0.f, 0.f, 0.f, 0.f);
    acc2[r] = make_float4(0.f, 0.f, 0.f, 0.f);
  }
  const float4* W14 = (const float4*)W1;
  const float4* W24 = (const float4*)W2;
  for (int k = 0; k < K; k += 4) {
    float4 u0 = W14[(size_t)(k + 0) * CQ + cq];
    float4 u1 = W14[(size_t)(k + 1) * CQ + cq];
    float4 u2 = W14[(size_t)(k + 2) * CQ + cq];
    float4 u3 = W14[(size_t)(k + 3) * CQ + cq];
    float4 v0 = W24[(size_t)(k + 0) * CQ + cq];
    float4 v1 = W24[(size_t)(k + 1) * CQ + cq];
    float4 v2 = W24[(size_t)(k + 2) * CQ + cq];
    float4 v3 = W24[(size_t)(k + 3) * CQ + cq];
#pragma unroll
    for (int r = 0; r < RP; r++) {
      float4 a = ((const float4*)Alds)[(rg * RP + r) * (K / 4) + (k >> 2)];
      acc1[r].x = fmaf(a.x, u0.x, acc1[r].x);
      acc1[r].y = fmaf(a.x, u0.y, acc1[r].y);
      acc1[r].z = fmaf(a.x, u0.z, acc1[r].z);
      acc1[r].w = fmaf(a.x, u0.w, acc1[r].w);
      acc1[r].x = fmaf(a.y, u1.x, acc1[r].x);
      acc1[r].y = fmaf(a.y, u1.y, acc1[r].y);
      acc1[r].z = fmaf(a.y, u1.z, acc1[r].z);
      acc1[r].w = fmaf(a.y, u1.w, acc1[r].w);
      acc1[r].x = fmaf(a.z, u2.x, acc1[r].x);
      acc1[r].y = fmaf(a.z, u2.y, acc1[r].y);
      acc1[r].z = fmaf(a.z, u2.z, acc1[r].z);
      acc1[r].w = fmaf(a.z, u2.w, acc1[r].w);
      acc1[r].x = fmaf(a.w, u3.x, acc1[r].x);
      acc1[r].y = fmaf(a.w, u3.y, acc1[r].y);
      acc1[r].z = fmaf(a.w, u3.z, acc1[r].z);
      acc1[r].w = fmaf(a.w, u3.w, acc1[r].w);
      acc2[r].x = fmaf(a.x, v0.x, acc2[r].x);
      acc2[r].y = fmaf(a.x, v0.y, acc2[r].y);
      acc2[r].z = fmaf(a.x, v0.z, acc2[r].z);
      acc2[r].w = fmaf(a.x, v0.w, acc2[r].w);
      acc2[r].x = fmaf(a.y, v1.x, acc2[r].x);
      acc2[r].y = fmaf(a.y, v1.y, acc2[r].y);
      acc2[r].z = fmaf(a.y, v1.z, acc2[r].z);
      acc2[r].w = fmaf(a.y, v1.w, acc2[r].w);
      acc2[r].x = fmaf(a.z, v2.x, acc2[r].x);
      acc2[r].y = fmaf(a.z, v2.y, acc2[r].y);
      acc2[r].z = fmaf(a.z, v2.z, acc2[r].z);
      acc2[r].w = fmaf(a.z, v2.w, acc2[r].w);
      acc2[r].x = fmaf(a.w, v3.x, acc2[r].x);
      acc2[r].y = fmaf(a.w, v3.y, acc2[r].y);
      acc2[r].z = fmaf(a.w, v3.z, acc2[r].z);
      acc2[r].w = fmaf(a.w, v3.w, acc2[r].w);
    }
  }
  float4 bb1 = b1 ? ((const float4*)b1)[cq] : make_float4(0.f, 0.f, 0.f, 0.f);
  float4 bb2 = b2 ? ((const float4*)b2)[cq] : make_float4(0.f, 0.f, 0.f, 0.f);
#pragma unroll
  for (int r = 0; r < RP; r++) {
    int row = row0 + rg * RP + r;
    if (row < M) {
      ((float4*)C1)[(size_t)row * CQ + cq] =
          make_float4(acc1[r].x + bb1.x, acc1[r].y + bb1.y, acc1[r].z + bb1.z,
                      acc1[r].w + bb1.w);
      ((float4*)C2)[(size_t)row * CQ + cq] =
          make_float4(acc2[r].x + bb2.x, acc2[r].y + bb2.y, acc2[r].z + bb2.z,
                      acc2[r].w + bb2.w);
    }
  }
}

// H=2 fused node pass. Lanes 0-31 = head0 (2 ch/lane), 32-63 = head1.
// Batch of 4 edges: we[k] from LDS read once, applied to 4 uniform ea rows.
template <int ELU>
__global__ __launch_bounds__(256) void node_fused2_kernel(
    const int* __restrict__ rowptr, const int* __restrict__ sperm,
    const float* __restrict__ ea_sorted, const float* __restrict__ We,
    const float* __restrict__ att, const float* __restrict__ xl,
    const float* __restrict__ xr, const float* __restrict__ bias,
    float* __restrict__ out, int Nn) {
  __shared__ float weLds[16 * 128];
  for (int i = threadIdx.x; i < 16 * 128 / 4; i += 256)
    ((float4*)weLds)[i] = ((const float4*)We)[i];
  __syncthreads();
  int wid = blockIdx.x * 4 + (threadIdx.x >> 6);
  if (wid >= Nn) return;
  int l = threadIdx.x & 63;
  int ch = ((l >> 5) << 6) | ((l & 31) << 1);  // head*64 + 2*q
  const float* wp = weLds + ch;
  float2 xr2 = *(const float2*)(xr + (size_t)wid * 128 + ch);
  float2 at2 = *(const float2*)(att + ch);
  int start = __builtin_amdgcn_readfirstlane(rowptr[wid]);
  int end = __builtin_amdgcn_readfirstlane(rowptr[wid + 1]);
  float m = -1e30f, sden = 0.f, accx = 0.f, accy = 0.f;
  float sax = 0.f, say = 0.f;
  for (int j = start; j < end; j += 4) {
    bool f1 = (j + 1 < end), f2 = (j + 2 < end), f3 = (j + 3 < end);
    int j1 = f1 ? j + 1 : j, j2 = f2 ? j + 2 : j, j3 = f3 ? j + 3 : j;
    int s0 = sperm[j], s1 = sperm[j1], s2 = sperm[j2], s3 = sperm[j3];
    float2 X0 = *(const float2*)(xl + (size_t)s0 * 128 + ch);
    float2 X1 = *(const float2*)(xl + (size_t)s1 * 128 + ch);
    float2 X2 = *(const float2*)(xl + (size_t)s2 * 128 + ch);
    float2 X3 = *(const float2*)(xl + (size_t)s3 * 128 + ch);
    const float* e0p = ea_sorted + (size_t)j * 16;
    const float* e1p = ea_sorted + (size_t)j1 * 16;
    const float* e2p = ea_sorted + (size_t)j2 * 16;
    const float* e3p = ea_sorted + (size_t)j3 * 16;
    float ex0 = 0.f, ey0 = 0.f, ex1 = 0.f, ey1 = 0.f;
    float ex2 = 0.f, ey2 = 0.f, ex3 = 0.f, ey3 = 0.f;
#pragma unroll
    for (int k = 0; k < 16; k++) {
      float2 w = *(const float2*)(wp + k * 128);
      float a0 = e0p[k], a1 = e1p[k], a2 = e2p[k], a3 = e3p[k];
      ex0 = fmaf(a0, w.x, ex0); ey0 = fmaf(a0, w.y, ey0);
      ex1 = fmaf(a1, w.x, ex1); ey1 = fmaf(a1, w.y, ey1);
      ex2 = fmaf(a2, w.x, ex2); ey2 = fmaf(a2, w.y, ey2);
      ex3 = fmaf(a3, w.x, ex3); ey3 = fmaf(a3, w.y, ey3);
    }
    float mx, my;
    mx = X0.x + xr2.x + ex0; my = X0.y + xr2.y + ey0;
    mx = (mx >= 0.f) ? mx : 0.2f * mx; my = (my >= 0.f) ? my : 0.2f * my;
    float p0 = fmaf(at2.x, mx, at2.y * my);
    mx = X1.x + xr2.x + ex1; my = X1.y + xr2.y + ey1;
    mx = (mx >= 0.f) ? mx : 0.2f * mx; my = (my >= 0.f) ? my : 0.2f * my;
    float p1 = fmaf(at2.x, mx, at2.y * my);
    mx = X2.x + xr2.x + ex2; my = X2.y + xr2.y + ey2;
    mx = (mx >= 0.f) ? mx : 0.2f * mx; my = (my >= 0.f) ? my : 0.2f * my;
    float p2 = fmaf(at2.x, mx, at2.y * my);
    mx = X3.x + xr2.x + ex3; my = X3.y + xr2.y + ey3;
    mx = (mx >= 0.f) ? mx : 0.2f * mx; my = (my >= 0.f) ? my : 0.2f * my;
    float p3 = fmaf(at2.x, mx, at2.y * my);
#pragma unroll
    for (int o = 1; o <= 16; o <<= 1) {
      p0 += __shfl_xor(p0, o, 64);
      p1 += __shfl_xor(p1, o, 64);
      p2 += __shfl_xor(p2, o, 64);
      p3 += __shfl_xor(p3, o, 64);
    }
    p1 = f1 ? p1 : -1e30f;
    p2 = f2 ? p2 : -1e30f;
    p3 = f3 ? p3 : -1e30f;
    float pm = fmaxf(fmaxf(p0, p1), fmaxf(p2, p3));
    float nm = fmaxf(m, pm);
    float r = __expf(m - nm);
    float q0 = __expf(p0 - nm), q1 = __expf(p1 - nm);
    float q2 = __expf(p2 - nm), q3 = __expf(p3 - nm);
    sden = fmaf(sden, r, (q0 + q1) + (q2 + q3));
    accx = fmaf(accx, r, fmaf(q0, X0.x, q1 * X1.x) + fmaf(q2, X2.x, q3 * X3.x));
    accy = fmaf(accy, r, fmaf(q0, X0.y, q1 * X1.y) + fmaf(q2, X2.y, q3 * X3.y));
    m = nm;
    sax += ex0 + (f1 ? ex1 : 0.f) + (f2 ? ex2 : 0.f) + (f3 ? ex3 : 0.f);
    say += ey0 + (f1 ? ey1 : 0.f) + (f2 ? ey2 : 0.f) + (f3 ? ey3 : 0.f);
  }
  // analytic self loop: eaW = mean of incident eaW (0 if isolated)
  {
    float denom = 1.f / fmaxf((float)(end - start), 1.f);
    float2 Xs = *(const float2*)(xl + (size_t)wid * 128 + ch);
    float mx = Xs.x + xr2.x + sax * denom;
    float my = Xs.y + xr2.y + say * denom;
    mx = (mx >= 0.f) ? mx : 0.2f * mx;
    my = (my >= 0.f) ? my : 0.2f * my;
    float p = fmaf(at2.x, mx, at2.y * my);
#pragma unroll
    for (int o = 1; o <= 16; o <<= 1) p += __shfl_xor(p, o, 64);
    float nm = fmaxf(m, p);
    float r = __expf(m - nm), ep = __expf(p - nm);
    sden = fmaf(sden, r, ep);
    accx = fmaf(accx, r, ep * Xs.x);
    accy = fmaf(accy, r, ep * Xs.y);
  }
  float inv = 1.f / sden;
  float2 b2 = *(const float2*)(bias + ch);
  float vx = fmaf(accx, inv, b2.x);
  float vy = fmaf(accy, inv, b2.y);
  if (ELU) {
    vx = (vx > 0.f) ? vx : expm1f(vx);
    vy = (vy > 0.f) ? vy : expm1f(vy);
  }
  *(float2*)(out + (size_t)wid * 128 + ch) = make_float2(vx, vy);
}

// H=1 fused node pass: full wave per edge, 1 ch/lane (64 ch), batch of 4.
__global__ __launch_bounds__(256) void node_fused1_kernel(
    const int* __restrict__ rowptr, const int* __restrict__ sperm,
    const float* __restrict__ ea_sorted, const float* __restrict__ We,
    const float* __restrict__ att, const float* __restrict__ xl,
    const float* __restrict__ xr, const float* __restrict__ bias,
    float* __restrict__ out, int Nn) {
  __shared__ float weLds[16 * 64];
  if (threadIdx.x < 256)
    ((float4*)weLds)[threadIdx.x] = ((const float4*)We)[threadIdx.x];
  __syncthreads();
  int wid = blockIdx.x * 4 + (threadIdx.x >> 6);
  if (wid >= Nn) return;
  int l = threadIdx.x & 63;
  const float* wp = weLds + l;
  float xr1 = xr[(size_t)wid * 64 + l];
  float a1 = att[l];
  int start = __builtin_amdgcn_readfirstlane(rowptr[wid]);
  int end = __builtin_amdgcn_readfirstlane(rowptr[wid + 1]);
  float m = -1e30f, sden = 0.f, acc = 0.f, sa = 0.f;
  for (int j = start; j < end; j += 4) {
    bool f1 = (j + 1 < end), f2 = (j + 2 < end), f3 = (j + 3 < end);
    int j1 = f1 ? j + 1 : j, j2 = f2 ? j + 2 : j, j3 = f3 ? j + 3 : j;
    int s0 = sperm[j], s1 = sperm[j1], s2 = sperm[j2], s3 = sperm[j3];
    float X0 = xl[(size_t)s0 * 64 + l];
    float X1 = xl[(size_t)s1 * 64 + l];
    float X2 = xl[(size_t)s2 * 64 + l];
    float X3 = xl[(size_t)s3 * 64 + l];
    const float* e0p = ea_sorted + (size_t)j * 16;
    const float* e1p = ea_sorted + (size_t)j1 * 16;
    const float* e2p = ea_sorted + (size_t)j2 * 16;
    const float* e3p = ea_sorted + (size_t)j3 * 16;
    float ex0 = 0.f, ex1 = 0.f, ex2 = 0.f, ex3 = 0.f;
#pragma unroll
    for (int k = 0; k < 16; k++) {
      float w = wp[k * 64];
      ex0 = fmaf(e0p[k], w, ex0);
      ex1 = fmaf(e1p[k], w, ex1);
      ex2 = fmaf(e2p[k], w, ex2);
      ex3 = fmaf(e3p[k], w, ex3);
    }
    float t;
    t = X0 + xr1 + ex0; t = (t >= 0.f) ? t : 0.2f * t; float p0 = a1 * t;
    t = X1 + xr1 + ex1; t = (t >= 0.f) ? t : 0.2f * t; float p1 = a1 * t;
    t = X2 + xr1 + ex2; t = (t >= 0.f) ? t : 0.2f * t; float p2 = a1 * t;
    t = X3 + xr1 + ex3; t = (t >= 0.f) ? t : 0.2f * t; float p3 = a1 * t;
#pragma unroll
    for (int o = 1; o <= 32; o <<= 1) {
      p0 += __shfl_xor(p0, o, 64);
      p1 += __shfl_xor(p1, o, 64);
      p2 += __shfl_xor(p2, o, 64);
      p3 += __shfl_xor(p3, o, 64);
    }
    p1 = f1 ? p1 : -1e30f;
    p2 = f2 ? p2 : -1e30f;
    p3 = f3 ? p3 : -1e30f;
    float pm = fmaxf(fmaxf(p0, p1), fmaxf(p2, p3));
    float nm = fmaxf(m, pm);
    float r = __expf(m - nm);
    float q0 = __expf(p0 - nm), q1 = __expf(p1 - nm);
    float q2 = __expf(p2 - nm), q3 = __expf(p3 - nm);
    sden = fmaf(sden, r, (q0 + q1) + (q2 + q3));
    acc = fmaf(acc, r, fmaf(q0, X0, q1 * X1) + fmaf(q2, X2, q3 * X3));
    m = nm;
    sa += ex0 + (f1 ? ex1 : 0.f) + (f2 ? ex2 : 0.f) + (f3 ? ex3 : 0.f);
  }
  // analytic self loop
  {
    float denom = 1.f / fmaxf((float)(end - start), 1.f);
    float Xs = xl[(size_t)wid * 64 + l];
    float t = Xs + xr1 + sa * denom;
    t = (t >= 0.f) ? t : 0.2f * t;
    float p = a1 * t;
#pragma unroll
    for (int o = 1; o <= 32; o <<= 1) p += __shfl_xor(p, o, 64);
    float nm = fmaxf(m, p);
    float r = __expf(m - nm), ep = __expf(p - nm);
    sden = fmaf(sden, r, ep);
    acc = fmaf(acc, r, ep * Xs);
  }
  out[(size_t)wid * 64 + l] = fmaf(acc, 1.f / sden, bias[l]);
}

// 4 edges per wave; 16 lanes x float4 per edge.
__global__ __launch_bounds__(256) void edge_mlp_kernel(
    const int* __restrict__ src, const int* __restrict__ dst,
    const float* __restrict__ aa, const float* __restrict__ bb,
    const float* __restrict__ Wm2, const float* __restrict__ bm2,
    float* __restrict__ out, int E) {
  int t = blockIdx.x * 256 + threadIdx.x;
  int eid = t >> 4;
  if (eid >= E) return;
  int g = threadIdx.x & 15;
  float4 w = ((const float4*)Wm2)[g];
  int s = src[eid], d = dst[eid];
  float4 za = ((const float4*)aa)[(size_t)s * 16 + g];
  float4 zb = ((const float4*)bb)[(size_t)d * 16 + g];
  float p = fmaxf(za.x + zb.x, 0.f) * w.x;
  p = fmaf(fmaxf(za.y + zb.y, 0.f), w.y, p);
  p = fmaf(fmaxf(za.z + zb.z, 0.f), w.z, p);
  p = fmaf(fmaxf(za.w + zb.w, 0.f), w.w, p);
#pragma unroll
  for (int o = 8; o > 0; o >>= 1) p += __shfl_xor(p, o, 64);
  if (g == 0) out[eid] = p + bm2[0];
}

extern "C" void kernel_launch(void* const* d_in, const int* in_sizes, int n_in,
                              void* d_out, int out_size, void* d_ws,
                              size_t ws_size, hipStream_t stream) {
  const float* x = (const float*)d_in[0];
  const int* ei = (const int*)d_in[1];
  const float* edge_attr = (const float*)d_in[2];
  const float* Wl1 = (const float*)d_in[3];
  const float* bl1 = (const float*)d_in[4];
  const float* Wr1 = (const float*)d_in[5];
  const float* br1 = (const float*)d_in[6];
  const float* We1 = (const float*)d_in[7];
  const float* att1 = (const float*)d_in[8];
  const float* b1 = (const float*)d_in[9];
  const float* Wl2 = (const float*)d_in[10];
  const float* bl2 = (const float*)d_in[11];
  const float* Wr2 = (const float*)d_in[12];
  const float* br2 = (const float*)d_in[13];
  const float* We2 = (const float*)d_in[14];
  const float* att2 = (const float*)d_in[15];
  const float* b2 = (const float*)d_in[16];
  const float* Wm1 = (const float*)d_in[17];
  const float* bm1 = (const float*)d_in[18];
  const float* Wm2 = (const float*)d_in[19];
  const float* bm2 = (const float*)d_in[20];

  const int Nn = in_sizes[0] / 128;  // 50000
  const int E = in_sizes[1] / 2;     // 800000
  const int* src = ei;
  const int* dst = ei + E;
  const int nb = (Nn + 255) / 256;

  char* ws = (char*)d_ws;
  size_t off = 0;
  auto alloc = [&](size_t bytes) -> char* {
    char* p = ws + off;
    off += (bytes + 255) & ~(size_t)255;
    return p;
  };
  int* cnt = (int*)alloc((size_t)Nn * 4);
  int* rowptr = (int*)alloc((size_t)(Nn + 1) * 4);
  int* cursor = (int*)alloc((size_t)Nn * 4);
  int* partial = (int*)alloc(256 * 4);
  int* sperm = (int*)alloc((size_t)E * 4);
  int* pperm = (int*)alloc((size_t)E * 4);
  float* ea_sorted = (float*)alloc((size_t)E * 16 * 4);
  float* xl = (float*)alloc((size_t)Nn * 128 * 4);
  float* xr = (float*)alloc((size_t)Nn * 128 * 4);
  float* h1 = (float*)alloc((size_t)Nn * 128 * 4);
  float* h2 = (float*)alloc((size_t)Nn * 64 * 4);
  float* aa = xl;  // reuse after layer-2 node pass
  float* bb = xr;

  hipMemsetAsync(cnt, 0, (size_t)Nn * 4, stream);

  // --- graph preprocessing ---
  cnt_kernel<<<(E + 255) / 256, 256, 0, stream>>>(dst, cnt, E);
  scan_blocksum_kernel<<<nb, 256, 0, stream>>>(cnt, partial, Nn);
  scan_partial_kernel<<<1, 256, 0, stream>>>(partial, rowptr, nb, Nn, E);
  scan_write_kernel<<<nb, 256, 0, stream>>>(cnt, partial, rowptr, cursor, Nn);
  csr_build_kernel<<<(E + 255) / 256, 256, 0, stream>>>(src, dst, cursor, sperm,
                                                        pperm, E);
  ea_scatter_kernel<<<(E * 16 + 255) / 256, 256, 0, stream>>>(edge_attr, pperm,
                                                              ea_sorted, E);

  // --- layer 1 (heads=2, hid=64) ---
  gemm2_kernel<128, 128><<<(Nn + 63) / 64, 256, 0, stream>>>(
      x, Wl1, bl1, xl, Wr1, br1, xr, Nn);
  node_fused2_kernel<1><<<(Nn + 3) / 4, 256, 0, stream>>>(
      rowptr, sperm, ea_sorted, We1, att1, xl, xr, b1, h1, Nn);

  // --- layer 2 (heads=1, out=64) ---
  gemm2_kernel<128, 64><<<(Nn + 63) / 64, 256, 0, stream>>>(
      h1, Wl2, bl2, xl, Wr2, br2, xr, Nn);
  node_fused1_kernel<<<(Nn + 3) / 4, 256, 0, stream>>>(
      rowptr, sperm, ea_sorted, We2, att2, xl, xr, b2, h2, Nn);

  // --- edge MLP, folded: z = relu(h2[s]@Wm1_top + h2[d]@Wm1_bot + bm1) ---
  gemm2_kernel<64, 64><<<(Nn + 63) / 64, 256, 0, stream>>>(
      h2, Wm1, nullptr, aa, Wm1 + 64 * 64, bm1, bb, Nn);
  edge_mlp_kernel<<<(E * 16 + 255) / 256, 256, 0, stream>>>(src, dst, aa, bb,
                                                            Wm2, bm2,
                                                            (float*)d_out, E);
}